// Round 6
// baseline (81.195 us; speedup 1.0000x reference)
//
#include <hip/hip_runtime.h>
#include <stdint.h>

#define NBITS  8
#define SLICE  1024
#define OUTF   512
#define INF    8192
#define TOPK   32
#define BATCHN 4096
#define NSLICE (BATCHN * NBITS)            // 32768 slices

#define ROWS    INF                        // 8192 table rows, 64 words each
#define DUMMY_B (ROWS * 64 * 4)            // BYTE offset of dummy row (fields=1)
#define TBL2_B  ((ROWS + 1) * 64 * 4)      // BYTE offset of complement table

// sel code (u16): bits[13:0] = global row (n*1024+s), bits[15:14] = table id
//   0 = main table (positive latent), 1 = complement table (negative),
//   2 = dummy row (zero latent; row bits = 0)

// monotone float<->sortable-key bijection
__device__ __forceinline__ uint32_t fkey_u(uint32_t u) {
  uint32_t m = ((uint32_t)((int32_t)u >> 31)) | 0x80000000u;
  return u ^ m;
}
__device__ __forceinline__ float kfloat(uint32_t k) {
  uint32_t u = (k & 0x80000000u) ? (k ^ 0x80000000u) : ~k;
  return __uint_as_float(u);
}

// ---------------------------------------------------------------------------
// prep: pack b = (W>=0)+(Wm>=0) in {0,1,2} as 4-bit fields, 8 cols per u32.
// Word w of row r holds columns {w + 64*i}, field i.  Also writes the
// complement table (2-b) and a dummy row of 1-fields (zero contribution).
// ---------------------------------------------------------------------------
__global__ __launch_bounds__(256) void prep_kernel(
    const float* __restrict__ W, const float* __restrict__ Wm,
    uint32_t* __restrict__ tbl)
{
  int tid = blockIdx.x * blockDim.x + threadIdx.x;   // 8192*64 threads
  int r = tid >> 6;        // row 0..8191  (= n*1024 + s)
  int w = tid & 63;        // word 0..63
  const float* wr = W  + (size_t)r * OUTF;
  const float* mr = Wm + (size_t)r * OUTF;
  uint32_t word = 0;
#pragma unroll
  for (int i = 0; i < 8; ++i) {
    int col = w + 64 * i;
    uint32_t b = (wr[col] >= 0.0f ? 1u : 0u) + (mr[col] >= 0.0f ? 1u : 0u);
    word |= b << (4 * i);
  }
  tbl[tid] = word;
  tbl[(TBL2_B / 4) + tid] = 0x22222222u - word;   // fields 2-b (b<=2, no borrow)
  if (tid < 64) tbl[(DUMMY_B / 4) + tid] = 0x11111111u;
}

// ---------------------------------------------------------------------------
// select: one wave per slice (b, n).  256-thr blocks, NO LDS, NO barriers.
//  - seeded value-space binary search for the exact top-32 threshold
//    (first probe at 0.42 of the value bracket; every probe validated
//    against the integer bracket, integer upper-mid fallback).
//  - early exit when count==32 (exact set, boundary ties provably excluded).
//  - fast path: prefix-scan slots, write packed u16 codes to global.
//  - fallback: full stable lowest-index-first tie handling (exact).
// ---------------------------------------------------------------------------
__global__ __launch_bounds__(256, 8) void select_kernel(
    const float* __restrict__ latent,
    uint16_t* __restrict__ selg, int* __restrict__ partial)
{
  const int slice = blockIdx.x * 4 + (threadIdx.x >> 6);  // 0..32767
  const int lane  = threadIdx.x & 63;
  const int b     = slice >> 3;
  const int nb    = slice & 7;

  // ---- load 16 contiguous values, map to sortable keys, track lane max ----
  const float4* src =
      (const float4*)(latent + (size_t)b * INF + (size_t)nb * SLICE + lane * 16);
  uint32_t key[16];
  uint32_t lmax = 0u;
#pragma unroll
  for (int q = 0; q < 4; ++q) {
    float4 f = src[q];
    float vv[4] = {f.x, f.y, f.z, f.w};
#pragma unroll
    for (int t = 0; t < 4; ++t) {
      uint32_t k = fkey_u(__float_as_uint(vv[t]));
      key[4*q+t] = k;
      lmax = lmax > k ? lmax : k;
    }
  }
  // sign from key:  v>0 <=> key>0x80000000 ; v<0 <=> key<0x7FFFFFFF

  // ---- seeded bounds (valid for ANY input) --------------------------------
  // bmin = wave-min of lane maxima (>=64 elems >= bmin => T >= bmin)
  // bmax = wave-max of lane maxima (= global max >= T)
  uint32_t bmin = lmax, bmax = lmax;
#pragma unroll
  for (int d = 1; d < 64; d <<= 1) {
    uint32_t tn = (uint32_t)__shfl_xor((int)bmin, d);
    uint32_t tx = (uint32_t)__shfl_xor((int)bmax, d);
    bmin = bmin < tn ? bmin : tn;
    bmax = bmax > tx ? bmax : tx;
  }

  // ---- threshold search: value-space probes, exact bracket ----------------
  uint32_t T = 0, midE = 0, cE = 0;
  bool fast = false;
  {
    uint32_t lo = bmin, hi = bmax;
    float frac = 0.42f;                                // Gaussian-informed seed
    while (lo < hi) {
      uint32_t d   = hi - lo;
      uint32_t mid = lo + (d >> 1) + (d & 1u);         // int upper-mid fallback
      float fl = kfloat(lo), fh = kfloat(hi);
      uint32_t km = fkey_u(__float_as_uint(fl + frac * (fh - fl)));
      frac = 0.5f;
      if (km > lo && km <= hi) mid = km;               // validated probe
      uint32_t c = 0;
#pragma unroll
      for (int j = 0; j < 16; ++j) c += (key[j] >= mid) ? 1u : 0u;
      int cnt = 0;
#pragma unroll
      for (int bb = 0; bb < 5; ++bb)
        cnt += (int)__popcll(__ballot((c >> bb) & 1u)) << bb;
      if (cnt == TOPK) { fast = true; midE = mid; cE = c; break; }
      if (cnt > TOPK) lo = mid; else hi = mid - 1u;
    }
    if (!fast) T = lo;
  }

  uint16_t* sb = selg + ((size_t)slice << 5);          // 32 codes per slice
  const uint32_t gbase = (uint32_t)(nb * SLICE + lane * 16);
  int nzl = 0;                               // per-lane taken-nonzero count

  if (fast) {
    // ---- fast path: take set is exactly {key >= midE}, no boundary ties ---
    int sc = (int)cE;
#pragma unroll
    for (int dd = 1; dd < 64; dd <<= 1) {
      int t = __shfl_up(sc, dd);
      if (lane >= dd) sc += t;
    }
    int slot = sc - (int)cE;                 // exclusive prefix of take counts
#pragma unroll
    for (int j = 0; j < 16; ++j) {
      uint32_t kk = key[j];
      if (kk >= midE) {
        bool ispos = kk > 0x80000000u;
        bool isneg = kk < 0x7FFFFFFFu;
        uint32_t code = ispos ? (gbase + j)
                      : (isneg ? ((gbase + j) | 0x4000u) : 0x8000u);
        sb[slot++] = (uint16_t)code;
        nzl += (ispos || isneg) ? 1 : 0;
      }
    }
  } else {
    // ---- fallback: stable lowest-index-first tie handling (exact) ---------
    int cgt = 0, ceq = 0;
#pragma unroll
    for (int j = 0; j < 16; ++j) { cgt += (key[j] > T); ceq += (key[j] == T); }
    int packed = (cgt << 16) | ceq;
    int sc = packed;
#pragma unroll
    for (int dd = 1; dd < 64; dd <<= 1) {
      int t = __shfl_up(sc, dd);
      if (lane >= dd) sc += t;
    }
    int tot     = __shfl(sc, 63);
    int total_g = tot >> 16;                 // # strictly greater than T
    int nties   = TOPK - total_g;            // ties to take, lowest index first
    int excl    = sc - packed;
    int posg    = excl >> 16;
    int pose    = excl & 0xFFFF;
#pragma unroll
    for (int j = 0; j < 16; ++j) {
      uint32_t kk  = key[j];
      bool isgt    = kk > T;
      bool iseq    = (kk == T);
      bool takeeq  = iseq && (pose < nties);
      bool take    = isgt || takeeq;
      bool ispos   = kk > 0x80000000u;
      bool isneg   = kk < 0x7FFFFFFFu;
      uint32_t code = ispos ? (gbase + j)
                    : (isneg ? ((gbase + j) | 0x4000u) : 0x8000u);
      int slot = isgt ? posg : (total_g + pose);
      if (take) sb[slot] = (uint16_t)code;
      posg += isgt ? 1 : 0;
      pose += iseq ? 1 : 0;
      nzl  += (take && (ispos || isneg)) ? 1 : 0;
    }
  }

  // wave-sum of nzl (<=16) via bit-serial ballots
  {
    int cnz = 0;
#pragma unroll
    for (int bb = 0; bb < 5; ++bb)
      cnz += (int)__popcll(__ballot((nzl >> bb) & 1)) << bb;
    if (lane == 0) partial[nb * BATCHN + b] = cnz;
  }
}

// ---------------------------------------------------------------------------
// gather: one block per batch row, 8 waves; wave n sums its slice's 32
// selected table rows.  Codes are wave-uniform -> scalar loads, SGPR-based
// addressing (near-zero VALU).  Then per-column S = 2*F - 64, cumsum over
// bits via LDS, store result[n][b][col].
// ---------------------------------------------------------------------------
__global__ __launch_bounds__(512, 4) void gather_kernel(
    const uint16_t* __restrict__ selg,
    const uint32_t* __restrict__ tbl,
    float* __restrict__ out)
{
  __shared__ float sums[NBITS][OUTF];

  const int b    = blockIdx.x;
  const int lane = threadIdx.x & 63;
  const int wv   = __builtin_amdgcn_readfirstlane(threadIdx.x >> 6);

  // ---- read this slice's 32 codes from a uniform address ------------------
  const uint32_t* sp32 =
      (const uint32_t*)(selg + (((size_t)b * NBITS + wv) << 5));
  uint32_t code2[16];
#pragma unroll
  for (int q = 0; q < 16; ++q) code2[q] = sp32[q];

  // ---- gather: 32 loads (SGPR base + lane*4), packed 4-bit accumulate -----
  const char* tb = (const char*)tbl;
  const uint32_t lb = (uint32_t)lane << 2;
  uint32_t wrd[32];
#pragma unroll
  for (int q = 0; q < 16; ++q) {
    uint32_t c2 = code2[q];
#pragma unroll
    for (int h = 0; h < 2; ++h) {
      uint32_t e  = (h ? (c2 >> 16) : c2) & 0xFFFFu;
      uint32_t r  = e & 0x3FFFu;
      uint32_t t2 = e >> 14;                 // 0 main, 1 complement, 2 dummy
      uint32_t byteoff = r * 256u +
          (t2 == 1u ? (uint32_t)TBL2_B : (t2 == 2u ? (uint32_t)DUMMY_B : 0u));
      wrd[2*q+h] = *(const uint32_t*)(tb + (size_t)byteoff + lb);
    }
  }
  __builtin_amdgcn_sched_barrier(0);         // keep gather loads in flight

  uint32_t acc0 = 0, acc1 = 0, tmp = 0;
  int inch = 0;
#pragma unroll
  for (int j = 0; j < 32; ++j) {
    tmp += wrd[j];
    if (++inch == 7 || j == 31) {            // <=7 words: 4-bit fields safe
      acc0 += tmp & 0x0F0F0F0Fu;
      acc1 += (tmp >> 4) & 0x0F0F0F0Fu;
      tmp = 0; inch = 0;
    }
  }

  // ---- per-column S = 2*F - 64, scaled ------------------------------------
  const float scale_n = 1.0f / (float)(1 << wv);   // 2^(6-n)*4/256 = 2^-n
#pragma unroll
  for (int i2 = 0; i2 < 4; ++i2) {
    int f0 = (int)((acc0 >> (8 * i2)) & 0xFFu);
    int f1 = (int)((acc1 >> (8 * i2)) & 0xFFu);
    sums[wv][lane + 128 * i2]      = scale_n * (float)(2 * f0 - 64);
    sums[wv][lane + 128 * i2 + 64] = scale_n * (float)(2 * f1 - 64);
  }

  __syncthreads();

  // ---- cumsum over bits, store result[n][b][col] --------------------------
  const int col = threadIdx.x;               // 0..511
  float racc = 0.0f;
  float* obase = out + 8 + (size_t)b * OUTF + col;
#pragma unroll
  for (int n2 = 0; n2 < NBITS; ++n2) {
    racc += sums[n2][col];
    obase[(size_t)n2 * BATCHN * OUTF] = racc;
  }
}

// ---------------------------------------------------------------------------
// finalize: latent_group[n] = (sum_b partial[n][b]) / BATCH
// ---------------------------------------------------------------------------
__global__ __launch_bounds__(512) void fin_kernel(
    const int* __restrict__ partial, float* __restrict__ out)
{
  const int wv   = threadIdx.x >> 6;
  const int lane = threadIdx.x & 63;
  const int* p = partial + wv * BATCHN;
  int s = 0;
#pragma unroll
  for (int k = 0; k < BATCHN / 64; ++k)
    s += p[lane + 64 * k];
#pragma unroll
  for (int d = 32; d >= 1; d >>= 1)
    s += __shfl_down(s, d);
  if (lane == 0) out[wv] = (float)s * (1.0f / (float)BATCHN);
}

extern "C" void kernel_launch(void* const* d_in, const int* in_sizes, int n_in,
                              void* d_out, int out_size, void* d_ws, size_t ws_size,
                              hipStream_t stream)
{
  const float* latent = (const float*)d_in[0];
  const float* W      = (const float*)d_in[1];
  const float* Wm     = (const float*)d_in[2];
  float* out = (float*)d_out;

  // workspace layout
  int*      partial = (int*)d_ws;                            // 128 KB
  uint16_t* selg    = (uint16_t*)((char*)d_ws + 131072);     // 2 MB (32768*32*2)
  uint32_t* tbl     = (uint32_t*)((char*)d_ws + 2228224);    // ~4.2 MB tables

  prep_kernel<<<(INF * 64) / 256, 256, 0, stream>>>(W, Wm, tbl);
  select_kernel<<<NSLICE / 4, 256, 0, stream>>>(latent, selg, partial);
  gather_kernel<<<BATCHN, 512, 0, stream>>>(selg, tbl, out);
  fin_kernel<<<1, 512, 0, stream>>>(partial, out);
}